// Round 7
// baseline (342.409 us; speedup 1.0000x reference)
//
#include <hip/hip_runtime.h>
#include <hip/hip_bf16.h>

// ---------------------------------------------------------------------------
// MinigridPPOLSTMAgent forward, round 10: 2-elems-per-block LSTM (4 waves/SIMD
// TLP) on top of round-9 (fast activations, dbuf GEMM, merged preps).
//   T=128, B=256, N=32768, HID=128, NFLAT=1024, NA=7
// Pipeline:
//   P  prep_all   : merged w_ih perm + conv w tables + w_hh per-thread blocks
//   K1 conv_fused : obs -> featb[N][p*64+co] fp16 (conv1 VALU, conv2/3 MFMA)
//   K3 gemm_mfma  : xproj[N,512] = featb @ wb^T; 128x128 tile, BK=32, dbuf
//   K4 lstm_bfly  : 128 blocks x 1024 thr = 2 batch elems/block (sub=tid>>9);
//                   per elem: 512 thr, 4 thr/cell, resident w_hh, DPP
//                   butterfly, v_exp/v_rcp activations, 1 barrier/step.
//                   4 waves/SIMD hides the serial dep-chain stalls that kept
//                   round-9 at VALUBusy 64%.
//   K5 heads      : out[n,8] = hid16 @ [actor;critic].T + b
// ---------------------------------------------------------------------------

#define N_IMG   32768
#define T_LEN   128
#define B_ENV   256
#define HID     128

typedef _Float16 f16x8 __attribute__((ext_vector_type(8)));
typedef _Float16 f16x2 __attribute__((ext_vector_type(2)));
typedef float    f32x4 __attribute__((ext_vector_type(4)));
typedef unsigned short ushort8v __attribute__((ext_vector_type(8)));
typedef unsigned short ushort4v __attribute__((ext_vector_type(4)));

// ---- fast transcendentals: v_exp_f32 / v_rcp_f32, no IEEE-div sequence ----
#if defined(__has_builtin)
#if __has_builtin(__builtin_amdgcn_exp2f)
#define FEXP2(x) __builtin_amdgcn_exp2f(x)
#endif
#if __has_builtin(__builtin_amdgcn_rcpf)
#define FRCP(x) __builtin_amdgcn_rcpf(x)
#endif
#endif
#ifndef FEXP2
#define FEXP2(x) exp2f(x)
#endif
#ifndef FRCP
#define FRCP(x) (1.0f / (x))
#endif

__device__ __forceinline__ float sigm_(float x) {
    return FRCP(1.0f + FEXP2(-1.44269504f * x));
}
__device__ __forceinline__ float tanh_(float x) {
    return fmaf(-2.0f, FRCP(1.0f + FEXP2(2.88539008f * x)), 1.0f);
}

__device__ __forceinline__ unsigned short f2h(float x) {
    _Float16 h = (_Float16)x;
    union { _Float16 h; unsigned short u; } un; un.h = h;
    return un.u;
}

#if defined(__has_builtin)
#if __has_builtin(__builtin_amdgcn_fdot2)
#define HAVE_FDOT2 1
#endif
#endif

__device__ __forceinline__ float dot2_(f16x2 a, f16x2 b, float c) {
#ifdef HAVE_FDOT2
    return __builtin_amdgcn_fdot2(a, b, c, false);
#else
    c = fmaf((float)a[0], (float)b[0], c);
    return fmaf((float)a[1], (float)b[1], c);
#endif
}

// literal-index pair extraction from f16x8 (shufflevector needs constants)
#define P0(v) __builtin_shufflevector(v, v, 0, 1)
#define P1(v) __builtin_shufflevector(v, v, 2, 3)
#define P2(v) __builtin_shufflevector(v, v, 4, 5)
#define P3(v) __builtin_shufflevector(v, v, 6, 7)

// quad butterfly sum via DPP quad_perm (xor1 = 0xB1, xor2 = 0x4E): pure VALU.
__device__ __forceinline__ float bfly_sum4(float x) {
    int y = __builtin_amdgcn_update_dpp(0, __float_as_int(x), 0xB1, 0xF, 0xF, true);
    x += __int_as_float(y);
    y = __builtin_amdgcn_update_dpp(0, __float_as_int(x), 0x4E, 0xF, 0xF, true);
    return x + __int_as_float(y);
}

#define GLDS16(g, l) __builtin_amdgcn_global_load_lds( \
    (const __attribute__((address_space(1))) unsigned int*)(g), \
    (__attribute__((address_space(3))) unsigned int*)(l), 16, 0, 0)

// ---------------------------------------------------------------------------
// P: merged prep.  blocks [0,2048): w_ih; [2048,2088): conv w; [2088,2344): w_hh
// ---------------------------------------------------------------------------
__global__ void prep_all(const float* __restrict__ w_ih, unsigned short* __restrict__ wb,
                         const float* __restrict__ w2, const float* __restrict__ w3,
                         unsigned short* __restrict__ wb2g, unsigned short* __restrict__ wb3g,
                         const float* __restrict__ w_hh, unsigned short* __restrict__ whhr)
{
    const int bid = blockIdx.x, tid = threadIdx.x;
    if (bid < 2048) {
        const int idx = bid * 256 + tid;              // < 524288
        const int np = idx >> 10, kk = idx & 1023;
        const int p = kk >> 6, co = kk & 63;
        const int g = np & 3, ci = np >> 2;
        wb[idx] = f2h(w_ih[(g * 128 + ci) * 1024 + co * 16 + p]);
    } else if (bid < 2088) {
        const int t = (bid - 2048) * 256 + tid;       // < 10240
        if (t < 2048) {
            const int j = t & 7, lane = (t >> 3) & 63, f = t >> 9;   // f = ky*2+ct
            const int ky = f >> 1, ct = f & 1;
            const int k = ((lane >> 4) << 3) + j, kx = k >> 4, ci = k & 15;
            wb2g[t] = f2h(w2[(ct * 16 + (lane & 15)) * 64 + ci * 4 + ky * 2 + kx]);
        } else {
            const int u = t - 2048;
            const int j = u & 7, lane = (u >> 3) & 63, f = u >> 9;   // f = ct*4+pos
            const int ct = f >> 2, pos = f & 3;
            const int ci = ((lane >> 4) << 3) + j;
            wb3g[u] = f2h(w3[(ct * 16 + (lane & 15)) * 128 + ci * 4 + pos]);
        }
    } else {
        const int idx = (bid - 2088) * 256 + tid;     // < 65536
        const int thr = idx >> 7, r = idx & 127;
        const int g = r >> 5, k = r & 31;
        const int ci = thr >> 2, s = thr & 3;
        whhr[idx] = f2h(w_hh[(g * 128 + ci) * 128 + s * 32 + k]);
    }
}

// ---------------------------------------------------------------------------
// K1: fused conv. 16 images / block, 2048 blocks, 256 thr (4 waves).
// ---------------------------------------------------------------------------
__global__ __launch_bounds__(256, 2) void conv_fused(
    const float* __restrict__ obs,
    const float* __restrict__ w1, const float* __restrict__ b1,
    const float* __restrict__ b2, const float* __restrict__ b3,
    const unsigned short* __restrict__ wb2g,
    const unsigned short* __restrict__ wb3g,
    unsigned short* __restrict__ featb)
{
    __shared__ __align__(16) unsigned char u1[25856];   // max(obs 9472, c2s 25856)
    __shared__ __align__(16) unsigned char u2[33024];   // max(c1s 18688, c3s 33024)
    __shared__ float w1s[192];
    __shared__ float b1s[16];

    float* s_obs = (float*)u1;                 // [img][148]
    unsigned short* c2s = (unsigned short*)u1; // [img][pix*32+ci], img stride 808
    unsigned short* c1s = (unsigned short*)u2; // [img][p*16+ci],  img stride 584
    unsigned short* c3s = (unsigned short*)u2; // [img][p*64+co],  img stride 1032

    const int tid = threadIdx.x, lane = tid & 63, wv = tid >> 6;
    const int base = blockIdx.x * 16;

    if (tid < 192) w1s[tid] = w1[tid];
    if (tid < 16)  b1s[tid] = b1[tid];
    for (int i = tid; i < 16 * 147; i += 256) {
        const int im = i / 147, r = i - im * 147;
        s_obs[im * 148 + r] = obs[(size_t)(base + im) * 147 + r];
    }
    __syncthreads();

    // ---- conv1 (fp32 VALU): thread=(img, p) -> c1s[img][p][ci0..15] fp16 ----
    {
        const int img = tid & 15;
        const float* ob = &s_obs[img * 148];
        for (int p = tid >> 4; p < 36; p += 16) {
            const int py = p / 6, px = p % 6;
            float o[12];
#pragma unroll
            for (int ky = 0; ky < 2; ky++)
#pragma unroll
                for (int kx = 0; kx < 2; kx++)
#pragma unroll
                    for (int cc = 0; cc < 3; cc++)
                        o[cc * 4 + ky * 2 + kx] = ob[((py + ky) * 7 + px + kx) * 3 + cc];
            unsigned short res[16];
#pragma unroll
            for (int ci = 0; ci < 16; ci++) {
                float a = b1s[ci];
#pragma unroll
                for (int q = 0; q < 12; q++) a = fmaf(o[q], w1s[ci * 12 + q], a);
                res[ci] = f2h(fmaxf(a, 0.0f));
            }
            *(ushort8v*)&c1s[img * 584 + p * 16]     = *(ushort8v*)&res[0];
            *(ushort8v*)&c1s[img * 584 + p * 16 + 8] = *(ushort8v*)&res[8];
        }
    }
    __syncthreads();

    // ---- conv2 (MFMA): site=(p, cotile); A=weights(M=co16), B=imgs(N=16) ----
    {
        const int ct = wv & 1, par = wv >> 1;
        const int img = lane & 15, kq = lane >> 4;
        f16x8 wA[2];
        wA[0] = *(const f16x8*)&wb2g[(0 + ct) * 512 + lane * 8];   // ky=0
        wA[1] = *(const f16x8*)&wb2g[(2 + ct) * 512 + lane * 8];   // ky=1
        const float4 b2v = *(const float4*)&b2[ct * 16 + kq * 4];
#pragma unroll 2
        for (int p = par; p < 25; p += 2) {
            const int py = p / 5, px = p % 5;
            f32x4 acc = {0.f, 0.f, 0.f, 0.f};
#pragma unroll
            for (int ky = 0; ky < 2; ky++) {
                const int pix = (py + ky) * 6 + px + (kq >> 1);
                const f16x8 bv = *(const f16x8*)&c1s[img * 584 + pix * 16 + (kq & 1) * 8];
                acc = __builtin_amdgcn_mfma_f32_16x16x32_f16(wA[ky], bv, acc, 0, 0, 0);
            }
            unsigned short r4[4];
            r4[0] = f2h(fmaxf(acc[0] + b2v.x, 0.0f));
            r4[1] = f2h(fmaxf(acc[1] + b2v.y, 0.0f));
            r4[2] = f2h(fmaxf(acc[2] + b2v.z, 0.0f));
            r4[3] = f2h(fmaxf(acc[3] + b2v.w, 0.0f));
            *(ushort4v*)&c2s[img * 808 + p * 32 + ct * 16 + kq * 4] = *(ushort4v*)&r4[0];
        }
    }
    __syncthreads();

    // ---- conv3 (MFMA): wave = cotile (4 x 16 co); 16 pixel-sites each ----
    {
        const int ct = wv;
        const int img = lane & 15, kq = lane >> 4;
        f16x8 wA3[4];
#pragma unroll
        for (int pos = 0; pos < 4; pos++)
            wA3[pos] = *(const f16x8*)&wb3g[(ct * 4 + pos) * 512 + lane * 8];
        const float4 b3v = *(const float4*)&b3[ct * 16 + kq * 4];
#pragma unroll 4
        for (int p = 0; p < 16; p++) {
            const int py = p >> 2, px = p & 3;
            f32x4 acc = {0.f, 0.f, 0.f, 0.f};
#pragma unroll
            for (int pos = 0; pos < 4; pos++) {
                const int pix = (py + (pos >> 1)) * 5 + px + (pos & 1);
                const f16x8 bv = *(const f16x8*)&c2s[img * 808 + pix * 32 + kq * 8];
                acc = __builtin_amdgcn_mfma_f32_16x16x32_f16(wA3[pos], bv, acc, 0, 0, 0);
            }
            unsigned short r4[4];
            r4[0] = f2h(fmaxf(acc[0] + b3v.x, 0.0f));
            r4[1] = f2h(fmaxf(acc[1] + b3v.y, 0.0f));
            r4[2] = f2h(fmaxf(acc[2] + b3v.z, 0.0f));
            r4[3] = f2h(fmaxf(acc[3] + b3v.w, 0.0f));
            *(ushort4v*)&c3s[img * 1032 + p * 64 + ct * 16 + kq * 4] = *(ushort4v*)&r4[0];
        }
    }
    __syncthreads();

    // ---- dump c3s -> featb (feat row already in permuted k'=p*64+co order) ----
#pragma unroll
    for (int i = 0; i < 8; i++) {
        const int gi = i * 2048 + tid * 8;
        const int img = gi >> 10, flat = gi & 1023;
        *(ushort8v*)&featb[(size_t)(base + img) * 1024 + flat] =
            *(const ushort8v*)&c3s[img * 1032 + flat];
    }
}

// ---------------------------------------------------------------------------
// K3: xproj[32768,512] = featb[32768,1024]_f16 @ wb[512,1024]_f16^T (fp32 out)
//   128x128 tile, BK=32, double-buffered stage-ahead, 1 barrier per K-step.
// ---------------------------------------------------------------------------
__global__ __launch_bounds__(256, 2) void gemm_xproj_mfma(
    const unsigned short* __restrict__ A,
    const unsigned short* __restrict__ W,
    float* __restrict__ C)
{
    __shared__ unsigned short As[2][128 * 32];
    __shared__ unsigned short Bs[2][128 * 32];

    const int tid  = threadIdx.x;
    const int bx = blockIdx.x & 3;
    const int by = blockIdx.x >> 2;
    const int m0 = by * 128, n0 = bx * 128;
    const int lane = tid & 63, wave = tid >> 6;
    const int wm = (wave >> 1) * 64, wn = (wave & 1) * 64;
    const int srow = tid >> 2, sseg = tid & 3;

    const unsigned short* Ag = A + (size_t)(m0 + srow) * 1024 + sseg * 8;
    const unsigned short* Wg = W + (size_t)(n0 + srow) * 1024 + sseg * 8;

    f32x4 acc[4][4];
#pragma unroll
    for (int i = 0; i < 4; i++)
#pragma unroll
        for (int j = 0; j < 4; j++) acc[i][j] = (f32x4){0.f, 0.f, 0.f, 0.f};

    const int fr = lane & 15, fq = lane >> 4;

#define STAGEK(bb, k0) do {                                                \
        GLDS16(Ag + (k0),             (char*)&As[bb][0] + tid * 16);       \
        GLDS16(Ag + (k0) + 64 * 1024, (char*)&As[bb][0] + tid * 16 + 4096);\
        GLDS16(Wg + (k0),             (char*)&Bs[bb][0] + tid * 16);       \
        GLDS16(Wg + (k0) + 64 * 1024, (char*)&Bs[bb][0] + tid * 16 + 4096);\
    } while (0)

    STAGEK(0, 0);
    asm volatile("s_waitcnt vmcnt(0)" ::: "memory");
    __syncthreads();

    int cur = 0;
    for (int ks = 0; ks < 32; ks++) {
        if (ks + 1 < 32) STAGEK(cur ^ 1, (ks + 1) * 32);   // fly under MFMA

        f16x8 af[4], bfv[4];
#pragma unroll
        for (int i = 0; i < 4; i++)
            af[i] = *(const f16x8*)&As[cur][(wm + i * 16 + fr) * 32 + fq * 8];
#pragma unroll
        for (int j = 0; j < 4; j++)
            bfv[j] = *(const f16x8*)&Bs[cur][(wn + j * 16 + fr) * 32 + fq * 8];
#pragma unroll
        for (int i = 0; i < 4; i++)
#pragma unroll
            for (int j = 0; j < 4; j++)
                acc[i][j] = __builtin_amdgcn_mfma_f32_16x16x32_f16(af[i], bfv[j], acc[i][j], 0, 0, 0);

        asm volatile("s_waitcnt vmcnt(0)" ::: "memory");
        __syncthreads();
        cur ^= 1;
    }
#undef STAGEK

    const int cr = fq * 4, cc = fr;
#pragma unroll
    for (int i = 0; i < 4; i++) {
#pragma unroll
        for (int j = 0; j < 4; j++) {
            float* cp = &C[(size_t)(m0 + wm + i * 16 + cr) * 512 + (n0 + wn + j * 16 + cc)];
#pragma unroll
            for (int r = 0; r < 4; r++)
                cp[(size_t)r * 512] = acc[i][j][r];
        }
    }
}

// ---------------------------------------------------------------------------
// K4: 1-barrier butterfly LSTM, 2 batch elems per block.
//   128 blocks x 1024 threads; sub = tid>>9 picks the elem, inner 512
//   threads are the round-9 structure (4 thr/cell, resident w_hh, DPP
//   butterfly, fast activations).  16 waves/block = 4 waves/SIMD
//   (amdgpu_waves_per_eu(4,4), VGPR<=128): doubles latency hiding of the
//   serial dep chain that capped round 9 at VALUBusy 64%.
// ---------------------------------------------------------------------------
__global__ __launch_bounds__(1024) __attribute__((amdgpu_waves_per_eu(4, 4)))
void lstm_bfly(
    const float* __restrict__ xproj, const float* __restrict__ done,
    const float* __restrict__ h0, const float* __restrict__ c0,
    const unsigned short* __restrict__ whhr,
    const float* __restrict__ b_ih, const float* __restrict__ b_hh,
    unsigned short* __restrict__ hid16, float* __restrict__ out)
{
    const int sub = threadIdx.x >> 9;          // which batch elem in block
    const int tid = threadIdx.x & 511;
    const int b   = (blockIdx.x << 1) | sub;
    const int ci  = tid >> 2;                  // cell 0..127
    const int s   = tid & 3;                   // k-quarter 0..3

    __shared__ __align__(16) _Float16 hbuf[2][2][HID];   // [sub][pingpong][cell]

    // ---- resident weights: w[g][i] = w_hh[g*128+ci][s*32 + i*8 .. +8) ----
    f16x8 w[4][4];
    {
        const unsigned short* wp = whhr + (size_t)tid * 128;
#pragma unroll
        for (int g = 0; g < 4; g++)
#pragma unroll
            for (int i = 0; i < 4; i++)
                w[g][i] = *(const f16x8*)&wp[g * 32 + i * 8];
    }
    // ---- this lane's gate row (original order): n = s*128 + ci ----
    const float bias_l = b_ih[s * 128 + ci] + b_hh[s * 128 + ci];

    // ---- redundant cell state (identical across the 4 lanes of a cell) ----
    float c = c0[b * HID + ci];
    float h = h0[b * HID + ci];
    float dcur = done[b];

    if (tid < HID)
        hbuf[sub][0][tid] = (_Float16)(h0[b * HID + tid] * (1.0f - dcur));

    // step-0 gate input (row ci*4+s thanks to the prep row-perm)
    float xq = bias_l + xproj[(size_t)b * 512 + ci * 4 + s];
    __syncthreads();

// one pair-block of the dot: 1 ds_read_b128 + 16 dot2 into chains c0..c3
#define DOTBLK(i, c0_, c1_, c2_, c3_)                                           \
    {                                                                           \
        const f16x8 hv8 = *(const f16x8*)&hbuf[sub][p][s * 32 + (i) * 8];       \
        const f16x2 hp0 = P0(hv8), hp1 = P1(hv8), hp2 = P2(hv8), hp3 = P3(hv8); \
        c0_ = dot2_(P0(w[0][i]), hp0, c0_); c0_ = dot2_(P1(w[0][i]), hp1, c0_); \
        c0_ = dot2_(P2(w[0][i]), hp2, c0_); c0_ = dot2_(P3(w[0][i]), hp3, c0_); \
        c1_ = dot2_(P0(w[1][i]), hp0, c1_); c1_ = dot2_(P1(w[1][i]), hp1, c1_); \
        c1_ = dot2_(P2(w[1][i]), hp2, c1_); c1_ = dot2_(P3(w[1][i]), hp3, c1_); \
        c2_ = dot2_(P0(w[2][i]), hp0, c2_); c2_ = dot2_(P1(w[2][i]), hp1, c2_); \
        c2_ = dot2_(P2(w[2][i]), hp2, c2_); c2_ = dot2_(P3(w[2][i]), hp3, c2_); \
        c3_ = dot2_(P0(w[3][i]), hp0, c3_); c3_ = dot2_(P1(w[3][i]), hp1, c3_); \
        c3_ = dot2_(P2(w[3][i]), hp2, c3_); c3_ = dot2_(P3(w[3][i]), hp3, c3_); \
    }

    int p = 0;
    for (int t = 0; t < T_LEN; t++) {
        // ---- prefetch next-step xproj/done (hides under the dot loop) ----
        const int tn = (t + 1 < T_LEN) ? t + 1 : t;
        const float xqn = bias_l + xproj[((size_t)tn * B_ENV + b) * 512 + ci * 4 + s];
        const float dnn = done[tn * B_ENV + b];

        // ---- 64 dot2 in 8 independent chains ----
        float a0 = (s == 0) ? xq : 0.0f;
        float a1 = (s == 1) ? xq : 0.0f;
        float a2 = (s == 2) ? xq : 0.0f;
        float a3 = (s == 3) ? xq : 0.0f;
        float b0 = 0.f, b1 = 0.f, b2 = 0.f, b3 = 0.f;
        DOTBLK(0, a0, a1, a2, a3)
        DOTBLK(1, b0, b1, b2, b3)
        DOTBLK(2, a0, a1, a2, a3)
        DOTBLK(3, b0, b1, b2, b3)
        a0 += b0; a1 += b1; a2 += b2; a3 += b3;

        // ---- DPP quad butterfly (pure VALU, no LDS) ----
        a0 = bfly_sum4(a0); a1 = bfly_sum4(a1);
        a2 = bfly_sum4(a2); a3 = bfly_sum4(a3);

        // ---- fast activations + update (identical in all 4 lanes) ----
        const float gi = sigm_(a0), gf = sigm_(a1);
        const float gg = tanh_(a2), go = sigm_(a3);
        const float m = 1.0f - dcur;
        c = fmaf(gf, c * m, gi * gg);
        h = go * tanh_(c);

        if (s == 0) {
            hid16[((size_t)t * B_ENV + b) * HID + ci] = f2h(h);
            hbuf[sub][p ^ 1][ci] = (_Float16)(h * (1.0f - dnn));
        }

        xq = xqn; dcur = dnn; p ^= 1;
        __syncthreads();
    }

    if (s == 0) {
        out[262144 + b * HID + ci] = h;
        out[294912 + b * HID + ci] = c;
    }
#undef DOTBLK
}

// ---------------------------------------------------------------------------
// K5: heads. out[n][0..6] = actor, out[n][7] = critic. 32 rows / block.
// ---------------------------------------------------------------------------
__global__ __launch_bounds__(256, 2) void heads_kernel(
    const unsigned short* __restrict__ hid16,
    const float* __restrict__ aw, const float* __restrict__ ab,
    const float* __restrict__ cw, const float* __restrict__ cb,
    float* __restrict__ out)
{
    __shared__ float hs[32 * 129];
    __shared__ float ws[8 * 130];
    __shared__ float bs[8];

    const int tid = threadIdx.x;
    const int n0 = blockIdx.x * 32;

    for (int i = tid; i < 1024; i += 256) {
        const int r = i >> 7, k = i & 127;
        ws[r * 130 + k] = (r < 7) ? aw[r * 128 + k] : cw[k];
    }
    if (tid < 8) bs[tid] = (tid < 7) ? ab[tid] : cb[0];
    // staged fp16 -> fp32 conversion, 8 halves per thread iteration
    for (int i = tid; i < 512; i += 256) {
        const int r = i >> 4, k8 = (i & 15) * 8;
        const ushort8v v = *(const ushort8v*)&hid16[(size_t)(n0 + r) * 128 + k8];
#pragma unroll
        for (int q = 0; q < 8; q++) {
            union { unsigned short u; _Float16 h; } un; un.u = v[q];
            hs[r * 129 + k8 + q] = (float)un.h;
        }
    }
    __syncthreads();

    const int r = tid >> 3, jj = tid & 7;
    float acc = bs[jj];
    const float* hp = &hs[r * 129];
    const float* wp = &ws[jj * 130];
#pragma unroll
    for (int k = 0; k < 128; k++) acc = fmaf(hp[k], wp[k], acc);
    out[(size_t)(n0 + r) * 8 + jj] = acc;
}

// ---------------------------------------------------------------------------
extern "C" void kernel_launch(void* const* d_in, const int* in_sizes, int n_in,
                              void* d_out, int out_size, void* d_ws, size_t ws_size,
                              hipStream_t stream)
{
    (void)in_sizes; (void)n_in; (void)out_size; (void)ws_size;

    const float* obs  = (const float*)d_in[0];
    const float* done = (const float*)d_in[1];
    const float* h0   = (const float*)d_in[2];
    const float* c0   = (const float*)d_in[3];
    const float* w1   = (const float*)d_in[4];
    const float* b1   = (const float*)d_in[5];
    const float* w2   = (const float*)d_in[6];
    const float* b2   = (const float*)d_in[7];
    const float* w3   = (const float*)d_in[8];
    const float* b3   = (const float*)d_in[9];
    const float* w_ih = (const float*)d_in[10];
    const float* w_hh = (const float*)d_in[11];
    const float* b_ih = (const float*)d_in[12];
    const float* b_hh = (const float*)d_in[13];
    const float* aw   = (const float*)d_in[14];
    const float* ab   = (const float*)d_in[15];
    const float* cw   = (const float*)d_in[16];
    const float* cb   = (const float*)d_in[17];
    float* out = (float*)d_out;

    unsigned short* featb = (unsigned short*)d_ws;     // 33,554,432 u16
    unsigned short* wb    = featb + 33554432ull;       //    524,288 u16
    unsigned short* wb2g  = wb    + 524288ull;         //      2,048 u16
    unsigned short* wb3g  = wb2g  + 2048ull;           //      8,192 u16
    float* xproj = (float*)(wb3g + 8192ull + 2048ull); // align pad; 16,777,216 f32
    unsigned short* hid16 = (unsigned short*)(xproj + 16777216ull); // 4,194,304 u16
    unsigned short* whhr  = hid16 + 4194304ull;        // 65,536 u16

    prep_all<<<2344, 256, 0, stream>>>(w_ih, wb, w2, w3, wb2g, wb3g, w_hh, whhr);
    conv_fused<<<2048, 256, 0, stream>>>(obs, w1, b1, b2, b3, wb2g, wb3g, featb);
    gemm_xproj_mfma<<<1024, 256, 0, stream>>>(featb, wb, xproj);
    lstm_bfly<<<128, 1024, 0, stream>>>(xproj, done, h0, c0, whhr, b_ih, b_hh, hid16, out);
    heads_kernel<<<1024, 256, 0, stream>>>(hid16, aw, ab, cw, cb, out);
}

// Round 8
// 306.205 us; speedup vs baseline: 1.1182x; 1.1182x over previous
//
#include <hip/hip_runtime.h>
#include <hip/hip_bf16.h>

// ---------------------------------------------------------------------------
// MinigridPPOLSTMAgent forward, round 11: 8-thr/cell LSTM (4 waves/SIMD with
// resident weights: 32 VGPR/thread weight slice <= the 128-reg cap).
//   T=128, B=256, N=32768, HID=128, NFLAT=1024, NA=7
// Pipeline:
//   P  prep_all   : merged w_ih perm + conv w tables + w_hh per-thread blocks
//                   (whhr layout: thread tid<1024 -> 2 gates x 32 cols)
//   K1 conv_fused : obs -> featb[N][p*64+co] fp16 (conv1 VALU, conv2/3 MFMA)
//   K3 gemm_mfma  : xproj[N,512] = featb @ wb^T; 128x128 tile, BK=32, dbuf
//   K4 lstm_bfly  : 256 blocks x 1024 thr, 1 elem/block, 8 thr/cell:
//                   kq=s&3 k-quarter, gp=s>>2 gate-pair; 32 dot2/thread;
//                   quad DPP butterfly + ds_swizzle xor4 pair exchange;
//                   fast activations; 1 barrier/step.  16 waves/block =
//                   4 waves/SIMD hides the stalls that capped round 6.
//   K5 heads      : out[n,8] = hid16 @ [actor;critic].T + b
// ---------------------------------------------------------------------------

#define N_IMG   32768
#define T_LEN   128
#define B_ENV   256
#define HID     128

typedef _Float16 f16x8 __attribute__((ext_vector_type(8)));
typedef _Float16 f16x2 __attribute__((ext_vector_type(2)));
typedef float    f32x4 __attribute__((ext_vector_type(4)));
typedef unsigned short ushort8v __attribute__((ext_vector_type(8)));
typedef unsigned short ushort4v __attribute__((ext_vector_type(4)));

// ---- fast transcendentals: v_exp_f32 / v_rcp_f32, no IEEE-div sequence ----
#if defined(__has_builtin)
#if __has_builtin(__builtin_amdgcn_exp2f)
#define FEXP2(x) __builtin_amdgcn_exp2f(x)
#endif
#if __has_builtin(__builtin_amdgcn_rcpf)
#define FRCP(x) __builtin_amdgcn_rcpf(x)
#endif
#endif
#ifndef FEXP2
#define FEXP2(x) exp2f(x)
#endif
#ifndef FRCP
#define FRCP(x) (1.0f / (x))
#endif

__device__ __forceinline__ float sigm_(float x) {
    return FRCP(1.0f + FEXP2(-1.44269504f * x));
}
__device__ __forceinline__ float tanh_(float x) {
    return fmaf(-2.0f, FRCP(1.0f + FEXP2(2.88539008f * x)), 1.0f);
}

__device__ __forceinline__ unsigned short f2h(float x) {
    _Float16 h = (_Float16)x;
    union { _Float16 h; unsigned short u; } un; un.h = h;
    return un.u;
}

#if defined(__has_builtin)
#if __has_builtin(__builtin_amdgcn_fdot2)
#define HAVE_FDOT2 1
#endif
#endif

__device__ __forceinline__ float dot2_(f16x2 a, f16x2 b, float c) {
#ifdef HAVE_FDOT2
    return __builtin_amdgcn_fdot2(a, b, c, false);
#else
    c = fmaf((float)a[0], (float)b[0], c);
    return fmaf((float)a[1], (float)b[1], c);
#endif
}

// literal-index pair extraction from f16x8 (shufflevector needs constants)
#define P0(v) __builtin_shufflevector(v, v, 0, 1)
#define P1(v) __builtin_shufflevector(v, v, 2, 3)
#define P2(v) __builtin_shufflevector(v, v, 4, 5)
#define P3(v) __builtin_shufflevector(v, v, 6, 7)

// quad butterfly sum via DPP quad_perm (xor1 = 0xB1, xor2 = 0x4E): pure VALU.
__device__ __forceinline__ float bfly_sum4(float x) {
    int y = __builtin_amdgcn_update_dpp(0, __float_as_int(x), 0xB1, 0xF, 0xF, true);
    x += __int_as_float(y);
    y = __builtin_amdgcn_update_dpp(0, __float_as_int(x), 0x4E, 0xF, 0xF, true);
    return x + __int_as_float(y);
}

// lane^4 exchange via ds_swizzle BitMode (xor=4, and=0x1F): offset 0x101F.
__device__ __forceinline__ float swz_xor4(float x) {
    return __int_as_float(__builtin_amdgcn_ds_swizzle(__float_as_int(x), 0x101F));
}

#define GLDS16(g, l) __builtin_amdgcn_global_load_lds( \
    (const __attribute__((address_space(1))) unsigned int*)(g), \
    (__attribute__((address_space(3))) unsigned int*)(l), 16, 0, 0)

// ---------------------------------------------------------------------------
// P: merged prep.  blocks [0,2048): w_ih; [2048,2088): conv w; [2088,2344): w_hh
//   whhr (new): idx = thr*64 + gg*32 + k,  thr<1024: ci=thr>>3, s=thr&7,
//   kq=s&3, gp=s>>2, g=gp*2+gg  ->  w_hh[(g*128+ci)*128 + kq*32 + k]
// ---------------------------------------------------------------------------
__global__ void prep_all(const float* __restrict__ w_ih, unsigned short* __restrict__ wb,
                         const float* __restrict__ w2, const float* __restrict__ w3,
                         unsigned short* __restrict__ wb2g, unsigned short* __restrict__ wb3g,
                         const float* __restrict__ w_hh, unsigned short* __restrict__ whhr)
{
    const int bid = blockIdx.x, tid = threadIdx.x;
    if (bid < 2048) {
        const int idx = bid * 256 + tid;              // < 524288
        const int np = idx >> 10, kk = idx & 1023;
        const int p = kk >> 6, co = kk & 63;
        const int g = np & 3, ci = np >> 2;
        wb[idx] = f2h(w_ih[(g * 128 + ci) * 1024 + co * 16 + p]);
    } else if (bid < 2088) {
        const int t = (bid - 2048) * 256 + tid;       // < 10240
        if (t < 2048) {
            const int j = t & 7, lane = (t >> 3) & 63, f = t >> 9;   // f = ky*2+ct
            const int ky = f >> 1, ct = f & 1;
            const int k = ((lane >> 4) << 3) + j, kx = k >> 4, ci = k & 15;
            wb2g[t] = f2h(w2[(ct * 16 + (lane & 15)) * 64 + ci * 4 + ky * 2 + kx]);
        } else {
            const int u = t - 2048;
            const int j = u & 7, lane = (u >> 3) & 63, f = u >> 9;   // f = ct*4+pos
            const int ct = f >> 2, pos = f & 3;
            const int ci = ((lane >> 4) << 3) + j;
            wb3g[u] = f2h(w3[(ct * 16 + (lane & 15)) * 128 + ci * 4 + pos]);
        }
    } else {
        const int idx = (bid - 2088) * 256 + tid;     // < 65536
        const int thr = idx >> 6, r = idx & 63;
        const int gg = r >> 5, k = r & 31;
        const int ci = thr >> 3, s = thr & 7;
        const int kq = s & 3, gp = s >> 2;
        const int g = gp * 2 + gg;
        whhr[idx] = f2h(w_hh[(g * 128 + ci) * 128 + kq * 32 + k]);
    }
}

// ---------------------------------------------------------------------------
// K1: fused conv. 16 images / block, 2048 blocks, 256 thr (4 waves).
// ---------------------------------------------------------------------------
__global__ __launch_bounds__(256, 2) void conv_fused(
    const float* __restrict__ obs,
    const float* __restrict__ w1, const float* __restrict__ b1,
    const float* __restrict__ b2, const float* __restrict__ b3,
    const unsigned short* __restrict__ wb2g,
    const unsigned short* __restrict__ wb3g,
    unsigned short* __restrict__ featb)
{
    __shared__ __align__(16) unsigned char u1[25856];   // max(obs 9472, c2s 25856)
    __shared__ __align__(16) unsigned char u2[33024];   // max(c1s 18688, c3s 33024)
    __shared__ float w1s[192];
    __shared__ float b1s[16];

    float* s_obs = (float*)u1;                 // [img][148]
    unsigned short* c2s = (unsigned short*)u1; // [img][pix*32+ci], img stride 808
    unsigned short* c1s = (unsigned short*)u2; // [img][p*16+ci],  img stride 584
    unsigned short* c3s = (unsigned short*)u2; // [img][p*64+co],  img stride 1032

    const int tid = threadIdx.x, lane = tid & 63, wv = tid >> 6;
    const int base = blockIdx.x * 16;

    if (tid < 192) w1s[tid] = w1[tid];
    if (tid < 16)  b1s[tid] = b1[tid];
    for (int i = tid; i < 16 * 147; i += 256) {
        const int im = i / 147, r = i - im * 147;
        s_obs[im * 148 + r] = obs[(size_t)(base + im) * 147 + r];
    }
    __syncthreads();

    // ---- conv1 (fp32 VALU): thread=(img, p) -> c1s[img][p][ci0..15] fp16 ----
    {
        const int img = tid & 15;
        const float* ob = &s_obs[img * 148];
        for (int p = tid >> 4; p < 36; p += 16) {
            const int py = p / 6, px = p % 6;
            float o[12];
#pragma unroll
            for (int ky = 0; ky < 2; ky++)
#pragma unroll
                for (int kx = 0; kx < 2; kx++)
#pragma unroll
                    for (int cc = 0; cc < 3; cc++)
                        o[cc * 4 + ky * 2 + kx] = ob[((py + ky) * 7 + px + kx) * 3 + cc];
            unsigned short res[16];
#pragma unroll
            for (int ci = 0; ci < 16; ci++) {
                float a = b1s[ci];
#pragma unroll
                for (int q = 0; q < 12; q++) a = fmaf(o[q], w1s[ci * 12 + q], a);
                res[ci] = f2h(fmaxf(a, 0.0f));
            }
            *(ushort8v*)&c1s[img * 584 + p * 16]     = *(ushort8v*)&res[0];
            *(ushort8v*)&c1s[img * 584 + p * 16 + 8] = *(ushort8v*)&res[8];
        }
    }
    __syncthreads();

    // ---- conv2 (MFMA): site=(p, cotile); A=weights(M=co16), B=imgs(N=16) ----
    {
        const int ct = wv & 1, par = wv >> 1;
        const int img = lane & 15, kq = lane >> 4;
        f16x8 wA[2];
        wA[0] = *(const f16x8*)&wb2g[(0 + ct) * 512 + lane * 8];   // ky=0
        wA[1] = *(const f16x8*)&wb2g[(2 + ct) * 512 + lane * 8];   // ky=1
        const float4 b2v = *(const float4*)&b2[ct * 16 + kq * 4];
#pragma unroll 2
        for (int p = par; p < 25; p += 2) {
            const int py = p / 5, px = p % 5;
            f32x4 acc = {0.f, 0.f, 0.f, 0.f};
#pragma unroll
            for (int ky = 0; ky < 2; ky++) {
                const int pix = (py + ky) * 6 + px + (kq >> 1);
                const f16x8 bv = *(const f16x8*)&c1s[img * 584 + pix * 16 + (kq & 1) * 8];
                acc = __builtin_amdgcn_mfma_f32_16x16x32_f16(wA[ky], bv, acc, 0, 0, 0);
            }
            unsigned short r4[4];
            r4[0] = f2h(fmaxf(acc[0] + b2v.x, 0.0f));
            r4[1] = f2h(fmaxf(acc[1] + b2v.y, 0.0f));
            r4[2] = f2h(fmaxf(acc[2] + b2v.z, 0.0f));
            r4[3] = f2h(fmaxf(acc[3] + b2v.w, 0.0f));
            *(ushort4v*)&c2s[img * 808 + p * 32 + ct * 16 + kq * 4] = *(ushort4v*)&r4[0];
        }
    }
    __syncthreads();

    // ---- conv3 (MFMA): wave = cotile (4 x 16 co); 16 pixel-sites each ----
    {
        const int ct = wv;
        const int img = lane & 15, kq = lane >> 4;
        f16x8 wA3[4];
#pragma unroll
        for (int pos = 0; pos < 4; pos++)
            wA3[pos] = *(const f16x8*)&wb3g[(ct * 4 + pos) * 512 + lane * 8];
        const float4 b3v = *(const float4*)&b3[ct * 16 + kq * 4];
#pragma unroll 4
        for (int p = 0; p < 16; p++) {
            const int py = p >> 2, px = p & 3;
            f32x4 acc = {0.f, 0.f, 0.f, 0.f};
#pragma unroll
            for (int pos = 0; pos < 4; pos++) {
                const int pix = (py + (pos >> 1)) * 5 + px + (pos & 1);
                const f16x8 bv = *(const f16x8*)&c2s[img * 808 + pix * 32 + kq * 8];
                acc = __builtin_amdgcn_mfma_f32_16x16x32_f16(wA3[pos], bv, acc, 0, 0, 0);
            }
            unsigned short r4[4];
            r4[0] = f2h(fmaxf(acc[0] + b3v.x, 0.0f));
            r4[1] = f2h(fmaxf(acc[1] + b3v.y, 0.0f));
            r4[2] = f2h(fmaxf(acc[2] + b3v.z, 0.0f));
            r4[3] = f2h(fmaxf(acc[3] + b3v.w, 0.0f));
            *(ushort4v*)&c3s[img * 1032 + p * 64 + ct * 16 + kq * 4] = *(ushort4v*)&r4[0];
        }
    }
    __syncthreads();

    // ---- dump c3s -> featb (feat row already in permuted k'=p*64+co order) ----
#pragma unroll
    for (int i = 0; i < 8; i++) {
        const int gi = i * 2048 + tid * 8;
        const int img = gi >> 10, flat = gi & 1023;
        *(ushort8v*)&featb[(size_t)(base + img) * 1024 + flat] =
            *(const ushort8v*)&c3s[img * 1032 + flat];
    }
}

// ---------------------------------------------------------------------------
// K3: xproj[32768,512] = featb[32768,1024]_f16 @ wb[512,1024]_f16^T (fp32 out)
//   128x128 tile, BK=32, double-buffered stage-ahead, 1 barrier per K-step.
// ---------------------------------------------------------------------------
__global__ __launch_bounds__(256, 2) void gemm_xproj_mfma(
    const unsigned short* __restrict__ A,
    const unsigned short* __restrict__ W,
    float* __restrict__ C)
{
    __shared__ unsigned short As[2][128 * 32];
    __shared__ unsigned short Bs[2][128 * 32];

    const int tid  = threadIdx.x;
    const int bx = blockIdx.x & 3;
    const int by = blockIdx.x >> 2;
    const int m0 = by * 128, n0 = bx * 128;
    const int lane = tid & 63, wave = tid >> 6;
    const int wm = (wave >> 1) * 64, wn = (wave & 1) * 64;
    const int srow = tid >> 2, sseg = tid & 3;

    const unsigned short* Ag = A + (size_t)(m0 + srow) * 1024 + sseg * 8;
    const unsigned short* Wg = W + (size_t)(n0 + srow) * 1024 + sseg * 8;

    f32x4 acc[4][4];
#pragma unroll
    for (int i = 0; i < 4; i++)
#pragma unroll
        for (int j = 0; j < 4; j++) acc[i][j] = (f32x4){0.f, 0.f, 0.f, 0.f};

    const int fr = lane & 15, fq = lane >> 4;

#define STAGEK(bb, k0) do {                                                \
        GLDS16(Ag + (k0),             (char*)&As[bb][0] + tid * 16);       \
        GLDS16(Ag + (k0) + 64 * 1024, (char*)&As[bb][0] + tid * 16 + 4096);\
        GLDS16(Wg + (k0),             (char*)&Bs[bb][0] + tid * 16);       \
        GLDS16(Wg + (k0) + 64 * 1024, (char*)&Bs[bb][0] + tid * 16 + 4096);\
    } while (0)

    STAGEK(0, 0);
    asm volatile("s_waitcnt vmcnt(0)" ::: "memory");
    __syncthreads();

    int cur = 0;
    for (int ks = 0; ks < 32; ks++) {
        if (ks + 1 < 32) STAGEK(cur ^ 1, (ks + 1) * 32);   // fly under MFMA

        f16x8 af[4], bfv[4];
#pragma unroll
        for (int i = 0; i < 4; i++)
            af[i] = *(const f16x8*)&As[cur][(wm + i * 16 + fr) * 32 + fq * 8];
#pragma unroll
        for (int j = 0; j < 4; j++)
            bfv[j] = *(const f16x8*)&Bs[cur][(wn + j * 16 + fr) * 32 + fq * 8];
#pragma unroll
        for (int i = 0; i < 4; i++)
#pragma unroll
            for (int j = 0; j < 4; j++)
                acc[i][j] = __builtin_amdgcn_mfma_f32_16x16x32_f16(af[i], bfv[j], acc[i][j], 0, 0, 0);

        asm volatile("s_waitcnt vmcnt(0)" ::: "memory");
        __syncthreads();
        cur ^= 1;
    }
#undef STAGEK

    const int cr = fq * 4, cc = fr;
#pragma unroll
    for (int i = 0; i < 4; i++) {
#pragma unroll
        for (int j = 0; j < 4; j++) {
            float* cp = &C[(size_t)(m0 + wm + i * 16 + cr) * 512 + (n0 + wn + j * 16 + cc)];
#pragma unroll
            for (int r = 0; r < 4; r++)
                cp[(size_t)r * 512] = acc[i][j][r];
        }
    }
}

// ---------------------------------------------------------------------------
// K4: 8-thr/cell butterfly LSTM.  256 blocks (1 elem each) x 1024 threads
//   (16 waves = 4/SIMD).  Thread (ci = tid>>3, s = tid&7): kq = s&3 owns
//   k-quarter [32kq,32kq+32), gp = s>>2 owns gate pair {2gp, 2gp+1}.
//   Weights: 2 gates x 32 cols = 32 VGPR (resident demand ~85 <= the
//   waves_per_eu(4,4) 128-reg cap -- round 7 failed because 2-elem demand
//   exceeded it).  32 dot2 in 4 chains; quad DPP butterfly sums k-quarters;
//   ds_swizzle xor4 exchanges the two gate-pair sums; fast activations;
//   fp16 h double-buffered in LDS; ONE barrier per step.
// ---------------------------------------------------------------------------
__global__ __launch_bounds__(1024) __attribute__((amdgpu_waves_per_eu(4, 4)))
void lstm_bfly(
    const float* __restrict__ xproj, const float* __restrict__ done,
    const float* __restrict__ h0, const float* __restrict__ c0,
    const unsigned short* __restrict__ whhr,
    const float* __restrict__ b_ih, const float* __restrict__ b_hh,
    unsigned short* __restrict__ hid16, float* __restrict__ out)
{
    const int b   = blockIdx.x;
    const int tid = threadIdx.x;
    const int ci  = tid >> 3;        // cell 0..127
    const int s   = tid & 7;
    const int kq  = s & 3;           // k-quarter
    const int gp  = s >> 2;          // gate pair {2gp, 2gp+1}

    __shared__ __align__(16) _Float16 hbuf[2][HID];

    // ---- resident weights: w[gg][i] = w_hh[(2gp+gg)*128+ci][kq*32+i*8 ..+8) ----
    f16x8 w[2][4];
    {
        const unsigned short* wp = whhr + (size_t)tid * 64;
#pragma unroll
        for (int gg = 0; gg < 2; gg++)
#pragma unroll
            for (int i = 0; i < 4; i++)
                w[gg][i] = *(const f16x8*)&wp[gg * 32 + i * 8];
    }
    // ---- this lane's xproj gate row: gate gq = 2gp + (kq&1), row ci*4+gq ----
    const int gq = 2 * gp + (kq & 1);
    const float bias_l = b_ih[gq * 128 + ci] + b_hh[gq * 128 + ci];
    const int xrow = ci * 4 + gq;
    const bool xact = (kq < 2);      // only kq 0/1 fold xq into their chain

    // ---- redundant cell state (identical across the 8 lanes of a cell) ----
    float c = c0[b * HID + ci];
    float h = h0[b * HID + ci];
    float dcur = done[b];

    if (tid < HID)
        hbuf[0][tid] = (_Float16)(h0[b * HID + tid] * (1.0f - dcur));

    float xq = bias_l + xproj[(size_t)b * 512 + xrow];
    __syncthreads();

// one pair-block of the dot: 1 ds_read_b128 + 8 dot2 into chains cA (gate
// 2gp) and cB (gate 2gp+1)
#define DOTBLK2(i, cA_, cB_)                                                    \
    {                                                                           \
        const f16x8 hv8 = *(const f16x8*)&hbuf[p][kq * 32 + (i) * 8];           \
        const f16x2 hp0 = P0(hv8), hp1 = P1(hv8), hp2 = P2(hv8), hp3 = P3(hv8); \
        cA_ = dot2_(P0(w[0][i]), hp0, cA_); cA_ = dot2_(P1(w[0][i]), hp1, cA_); \
        cA_ = dot2_(P2(w[0][i]), hp2, cA_); cA_ = dot2_(P3(w[0][i]), hp3, cA_); \
        cB_ = dot2_(P0(w[1][i]), hp0, cB_); cB_ = dot2_(P1(w[1][i]), hp1, cB_); \
        cB_ = dot2_(P2(w[1][i]), hp2, cB_); cB_ = dot2_(P3(w[1][i]), hp3, cB_); \
    }

    int p = 0;
    for (int t = 0; t < T_LEN; t++) {
        // ---- prefetch next-step xproj/done (hides under the dot loop) ----
        const int tn = (t + 1 < T_LEN) ? t + 1 : t;
        const float xqn = bias_l + xproj[((size_t)tn * B_ENV + b) * 512 + xrow];
        const float dnn = done[tn * B_ENV + b];

        // ---- 32 dot2 in 4 chains; xq folded by kq==0 (chain A) / kq==1 (B) ----
        float aA = (xact && kq == 0) ? xq : 0.0f;
        float aB = (xact && kq == 1) ? xq : 0.0f;
        float bA = 0.f, bB = 0.f;
        DOTBLK2(0, aA, aB)
        DOTBLK2(1, bA, bB)
        DOTBLK2(2, aA, aB)
        DOTBLK2(3, bA, bB)
        float sA = aA + bA, sB = aB + bB;

        // ---- quad DPP butterfly: sum the 4 k-quarters of this gate pair ----
        sA = bfly_sum4(sA); sB = bfly_sum4(sB);

        // ---- xor4 exchange: get the other pair's sums ----
        const float oA = swz_xor4(sA);
        const float oB = swz_xor4(sB);

        // ---- map to i,f,g,o (gp==0 holds i,f; gp==1 holds g,o) ----
        const float vi = (gp == 0) ? sA : oA;
        const float vf = (gp == 0) ? sB : oB;
        const float vg = (gp == 0) ? oA : sA;
        const float vo = (gp == 0) ? oB : sB;

        // ---- fast activations + update (identical in all 8 lanes) ----
        const float gi = sigm_(vi), gf = sigm_(vf);
        const float gg = tanh_(vg), go = sigm_(vo);
        const float m = 1.0f - dcur;
        c = fmaf(gf, c * m, gi * gg);
        h = go * tanh_(c);

        if (s == 0) {
            hid16[((size_t)t * B_ENV + b) * HID + ci] = f2h(h);
            hbuf[p ^ 1][ci] = (_Float16)(h * (1.0f - dnn));
        }

        xq = xqn; dcur = dnn; p ^= 1;
        __syncthreads();
    }

    if (s == 0) {
        out[262144 + b * HID + ci] = h;
        out[294912 + b * HID + ci] = c;
    }
#undef DOTBLK2
}

// ---------------------------------------------------------------------------
// K5: heads. out[n][0..6] = actor, out[n][7] = critic. 32 rows / block.
// ---------------------------------------------------------------------------
__global__ __launch_bounds__(256, 2) void heads_kernel(
    const unsigned short* __restrict__ hid16,
    const float* __restrict__ aw, const float* __restrict__ ab,
    const float* __restrict__ cw, const float* __restrict__ cb,
    float* __restrict__ out)
{
    __shared__ float hs[32 * 129];
    __shared__ float ws[8 * 130];
    __shared__ float bs[8];

    const int tid = threadIdx.x;
    const int n0 = blockIdx.x * 32;

    for (int i = tid; i < 1024; i += 256) {
        const int r = i >> 7, k = i & 127;
        ws[r * 130 + k] = (r < 7) ? aw[r * 128 + k] : cw[k];
    }
    if (tid < 8) bs[tid] = (tid < 7) ? ab[tid] : cb[0];
    // staged fp16 -> fp32 conversion, 8 halves per thread iteration
    for (int i = tid; i < 512; i += 256) {
        const int r = i >> 4, k8 = (i & 15) * 8;
        const ushort8v v = *(const ushort8v*)&hid16[(size_t)(n0 + r) * 128 + k8];
#pragma unroll
        for (int q = 0; q < 8; q++) {
            union { unsigned short u; _Float16 h; } un; un.u = v[q];
            hs[r * 129 + k8 + q] = (float)un.h;
        }
    }
    __syncthreads();

    const int r = tid >> 3, jj = tid & 7;
    float acc = bs[jj];
    const float* hp = &hs[r * 129];
    const float* wp = &ws[jj * 130];
#pragma unroll
    for (int k = 0; k < 128; k++) acc = fmaf(hp[k], wp[k], acc);
    out[(size_t)(n0 + r) * 8 + jj] = acc;
}

// ---------------------------------------------------------------------------
extern "C" void kernel_launch(void* const* d_in, const int* in_sizes, int n_in,
                              void* d_out, int out_size, void* d_ws, size_t ws_size,
                              hipStream_t stream)
{
    (void)in_sizes; (void)n_in; (void)out_size; (void)ws_size;

    const float* obs  = (const float*)d_in[0];
    const float* done = (const float*)d_in[1];
    const float* h0   = (const float*)d_in[2];
    const float* c0   = (const float*)d_in[3];
    const float* w1   = (const float*)d_in[4];
    const float* b1   = (const float*)d_in[5];
    const float* w2   = (const float*)d_in[6];
    const float* b2   = (const float*)d_in[7];
    const float* w3   = (const float*)d_in[8];
    const float* b3   = (const float*)d_in[9];
    const float* w_ih = (const float*)d_in[10];
    const float* w_hh = (const float*)d_in[11];
    const float* b_ih = (const float*)d_in[12];
    const float* b_hh = (const float*)d_in[13];
    const float* aw   = (const float*)d_in[14];
    const float* ab   = (const float*)d_in[15];
    const float* cw   = (const float*)d_in[16];
    const float* cb   = (const float*)d_in[17];
    float* out = (float*)d_out;

    unsigned short* featb = (unsigned short*)d_ws;     // 33,554,432 u16
    unsigned short* wb    = featb + 33554432ull;       //    524,288 u16
    unsigned short* wb2g  = wb    + 524288ull;         //      2,048 u16
    unsigned short* wb3g  = wb2g  + 2048ull;           //      8,192 u16
    float* xproj = (float*)(wb3g + 8192ull + 2048ull); // align pad; 16,777,216 f32
    unsigned short* hid16 = (unsigned short*)(xproj + 16777216ull); // 4,194,304 u16
    unsigned short* whhr  = hid16 + 4194304ull;        // 65,536 u16

    prep_all<<<2344, 256, 0, stream>>>(w_ih, wb, w2, w3, wb2g, wb3g, w_hh, whhr);
    conv_fused<<<2048, 256, 0, stream>>>(obs, w1, b1, b2, b3, wb2g, wb3g, featb);
    gemm_xproj_mfma<<<1024, 256, 0, stream>>>(featb, wb, xproj);
    lstm_bfly<<<256, 1024, 0, stream>>>(xproj, done, h0, c0, whhr, b_ih, b_hh, hid16, out);
    heads_kernel<<<1024, 256, 0, stream>>>(hid16, aw, ab, cw, cb, out);
}

// Round 9
// 269.165 us; speedup vs baseline: 1.2721x; 1.1376x over previous
//
#include <hip/hip_runtime.h>
#include <hip/hip_bf16.h>

// ---------------------------------------------------------------------------
// MinigridPPOLSTMAgent forward, round 12: round-6 config restored (best known:
// 281.6 us) + XCD-chunked swizzle on the GEMM grid.
//   T=128, B=256, N=32768, HID=128, NFLAT=1024, NA=7
// Pipeline:
//   P  prep_all   : merged w_ih perm + conv w tables + w_hh per-thread blocks
//   K1 conv_fused : obs -> featb[N][p*64+co] fp16 (conv1 VALU, conv2/3 MFMA)
//   K3 gemm_mfma  : xproj[N,512] = featb @ wb^T; 128x128 tile, BK=32, dbuf,
//                   XCD-chunked blockIdx swizzle (A-panel L2 locality).
//   K4 lstm_bfly  : 256 blocks x 512 thr (round-6 winner, 92 us): 4 thr/cell,
//                   64-VGPR resident w_hh (waves_per_eu(2,2)), DPP quad
//                   butterfly, v_exp/v_rcp activations, 1 barrier/step.
//   K5 heads      : out[n,8] = hid16 @ [actor;critic].T + b
// ---------------------------------------------------------------------------

#define N_IMG   32768
#define T_LEN   128
#define B_ENV   256
#define HID     128

typedef _Float16 f16x8 __attribute__((ext_vector_type(8)));
typedef _Float16 f16x2 __attribute__((ext_vector_type(2)));
typedef float    f32x4 __attribute__((ext_vector_type(4)));
typedef unsigned short ushort8v __attribute__((ext_vector_type(8)));
typedef unsigned short ushort4v __attribute__((ext_vector_type(4)));

// ---- fast transcendentals: v_exp_f32 / v_rcp_f32, no IEEE-div sequence ----
#if defined(__has_builtin)
#if __has_builtin(__builtin_amdgcn_exp2f)
#define FEXP2(x) __builtin_amdgcn_exp2f(x)
#endif
#if __has_builtin(__builtin_amdgcn_rcpf)
#define FRCP(x) __builtin_amdgcn_rcpf(x)
#endif
#endif
#ifndef FEXP2
#define FEXP2(x) exp2f(x)
#endif
#ifndef FRCP
#define FRCP(x) (1.0f / (x))
#endif

__device__ __forceinline__ float sigm_(float x) {
    return FRCP(1.0f + FEXP2(-1.44269504f * x));
}
__device__ __forceinline__ float tanh_(float x) {
    return fmaf(-2.0f, FRCP(1.0f + FEXP2(2.88539008f * x)), 1.0f);
}

__device__ __forceinline__ unsigned short f2h(float x) {
    _Float16 h = (_Float16)x;
    union { _Float16 h; unsigned short u; } un; un.h = h;
    return un.u;
}

#if defined(__has_builtin)
#if __has_builtin(__builtin_amdgcn_fdot2)
#define HAVE_FDOT2 1
#endif
#endif

__device__ __forceinline__ float dot2_(f16x2 a, f16x2 b, float c) {
#ifdef HAVE_FDOT2
    return __builtin_amdgcn_fdot2(a, b, c, false);
#else
    c = fmaf((float)a[0], (float)b[0], c);
    return fmaf((float)a[1], (float)b[1], c);
#endif
}

// literal-index pair extraction from f16x8 (shufflevector needs constants)
#define P0(v) __builtin_shufflevector(v, v, 0, 1)
#define P1(v) __builtin_shufflevector(v, v, 2, 3)
#define P2(v) __builtin_shufflevector(v, v, 4, 5)
#define P3(v) __builtin_shufflevector(v, v, 6, 7)

// quad butterfly sum via DPP quad_perm (xor1 = 0xB1, xor2 = 0x4E): pure VALU.
__device__ __forceinline__ float bfly_sum4(float x) {
    int y = __builtin_amdgcn_update_dpp(0, __float_as_int(x), 0xB1, 0xF, 0xF, true);
    x += __int_as_float(y);
    y = __builtin_amdgcn_update_dpp(0, __float_as_int(x), 0x4E, 0xF, 0xF, true);
    return x + __int_as_float(y);
}

#define GLDS16(g, l) __builtin_amdgcn_global_load_lds( \
    (const __attribute__((address_space(1))) unsigned int*)(g), \
    (__attribute__((address_space(3))) unsigned int*)(l), 16, 0, 0)

// ---------------------------------------------------------------------------
// P: merged prep.  blocks [0,2048): w_ih; [2048,2088): conv w; [2088,2344): w_hh
//   whhr (round-6 layout): thr = idx>>7 owns 128 halfs:
//   whhr[thr*128 + g*32 + k] = w_hh[(g*128+(thr>>2))*128 + (thr&3)*32 + k]
// ---------------------------------------------------------------------------
__global__ void prep_all(const float* __restrict__ w_ih, unsigned short* __restrict__ wb,
                         const float* __restrict__ w2, const float* __restrict__ w3,
                         unsigned short* __restrict__ wb2g, unsigned short* __restrict__ wb3g,
                         const float* __restrict__ w_hh, unsigned short* __restrict__ whhr)
{
    const int bid = blockIdx.x, tid = threadIdx.x;
    if (bid < 2048) {
        const int idx = bid * 256 + tid;              // < 524288
        const int np = idx >> 10, kk = idx & 1023;
        const int p = kk >> 6, co = kk & 63;
        const int g = np & 3, ci = np >> 2;
        wb[idx] = f2h(w_ih[(g * 128 + ci) * 1024 + co * 16 + p]);
    } else if (bid < 2088) {
        const int t = (bid - 2048) * 256 + tid;       // < 10240
        if (t < 2048) {
            const int j = t & 7, lane = (t >> 3) & 63, f = t >> 9;   // f = ky*2+ct
            const int ky = f >> 1, ct = f & 1;
            const int k = ((lane >> 4) << 3) + j, kx = k >> 4, ci = k & 15;
            wb2g[t] = f2h(w2[(ct * 16 + (lane & 15)) * 64 + ci * 4 + ky * 2 + kx]);
        } else {
            const int u = t - 2048;
            const int j = u & 7, lane = (u >> 3) & 63, f = u >> 9;   // f = ct*4+pos
            const int ct = f >> 2, pos = f & 3;
            const int ci = ((lane >> 4) << 3) + j;
            wb3g[u] = f2h(w3[(ct * 16 + (lane & 15)) * 128 + ci * 4 + pos]);
        }
    } else {
        const int idx = (bid - 2088) * 256 + tid;     // < 65536
        const int thr = idx >> 7, r = idx & 127;
        const int g = r >> 5, k = r & 31;
        const int ci = thr >> 2, s = thr & 3;
        whhr[idx] = f2h(w_hh[(g * 128 + ci) * 128 + s * 32 + k]);
    }
}

// ---------------------------------------------------------------------------
// K1: fused conv. 16 images / block, 2048 blocks, 256 thr (4 waves).
// ---------------------------------------------------------------------------
__global__ __launch_bounds__(256, 2) void conv_fused(
    const float* __restrict__ obs,
    const float* __restrict__ w1, const float* __restrict__ b1,
    const float* __restrict__ b2, const float* __restrict__ b3,
    const unsigned short* __restrict__ wb2g,
    const unsigned short* __restrict__ wb3g,
    unsigned short* __restrict__ featb)
{
    __shared__ __align__(16) unsigned char u1[25856];   // max(obs 9472, c2s 25856)
    __shared__ __align__(16) unsigned char u2[33024];   // max(c1s 18688, c3s 33024)
    __shared__ float w1s[192];
    __shared__ float b1s[16];

    float* s_obs = (float*)u1;                 // [img][148]
    unsigned short* c2s = (unsigned short*)u1; // [img][pix*32+ci], img stride 808
    unsigned short* c1s = (unsigned short*)u2; // [img][p*16+ci],  img stride 584
    unsigned short* c3s = (unsigned short*)u2; // [img][p*64+co],  img stride 1032

    const int tid = threadIdx.x, lane = tid & 63, wv = tid >> 6;
    const int base = blockIdx.x * 16;

    if (tid < 192) w1s[tid] = w1[tid];
    if (tid < 16)  b1s[tid] = b1[tid];
    for (int i = tid; i < 16 * 147; i += 256) {
        const int im = i / 147, r = i - im * 147;
        s_obs[im * 148 + r] = obs[(size_t)(base + im) * 147 + r];
    }
    __syncthreads();

    // ---- conv1 (fp32 VALU): thread=(img, p) -> c1s[img][p][ci0..15] fp16 ----
    {
        const int img = tid & 15;
        const float* ob = &s_obs[img * 148];
        for (int p = tid >> 4; p < 36; p += 16) {
            const int py = p / 6, px = p % 6;
            float o[12];
#pragma unroll
            for (int ky = 0; ky < 2; ky++)
#pragma unroll
                for (int kx = 0; kx < 2; kx++)
#pragma unroll
                    for (int cc = 0; cc < 3; cc++)
                        o[cc * 4 + ky * 2 + kx] = ob[((py + ky) * 7 + px + kx) * 3 + cc];
            unsigned short res[16];
#pragma unroll
            for (int ci = 0; ci < 16; ci++) {
                float a = b1s[ci];
#pragma unroll
                for (int q = 0; q < 12; q++) a = fmaf(o[q], w1s[ci * 12 + q], a);
                res[ci] = f2h(fmaxf(a, 0.0f));
            }
            *(ushort8v*)&c1s[img * 584 + p * 16]     = *(ushort8v*)&res[0];
            *(ushort8v*)&c1s[img * 584 + p * 16 + 8] = *(ushort8v*)&res[8];
        }
    }
    __syncthreads();

    // ---- conv2 (MFMA): site=(p, cotile); A=weights(M=co16), B=imgs(N=16) ----
    {
        const int ct = wv & 1, par = wv >> 1;
        const int img = lane & 15, kq = lane >> 4;
        f16x8 wA[2];
        wA[0] = *(const f16x8*)&wb2g[(0 + ct) * 512 + lane * 8];   // ky=0
        wA[1] = *(const f16x8*)&wb2g[(2 + ct) * 512 + lane * 8];   // ky=1
        const float4 b2v = *(const float4*)&b2[ct * 16 + kq * 4];
#pragma unroll 2
        for (int p = par; p < 25; p += 2) {
            const int py = p / 5, px = p % 5;
            f32x4 acc = {0.f, 0.f, 0.f, 0.f};
#pragma unroll
            for (int ky = 0; ky < 2; ky++) {
                const int pix = (py + ky) * 6 + px + (kq >> 1);
                const f16x8 bv = *(const f16x8*)&c1s[img * 584 + pix * 16 + (kq & 1) * 8];
                acc = __builtin_amdgcn_mfma_f32_16x16x32_f16(wA[ky], bv, acc, 0, 0, 0);
            }
            unsigned short r4[4];
            r4[0] = f2h(fmaxf(acc[0] + b2v.x, 0.0f));
            r4[1] = f2h(fmaxf(acc[1] + b2v.y, 0.0f));
            r4[2] = f2h(fmaxf(acc[2] + b2v.z, 0.0f));
            r4[3] = f2h(fmaxf(acc[3] + b2v.w, 0.0f));
            *(ushort4v*)&c2s[img * 808 + p * 32 + ct * 16 + kq * 4] = *(ushort4v*)&r4[0];
        }
    }
    __syncthreads();

    // ---- conv3 (MFMA): wave = cotile (4 x 16 co); 16 pixel-sites each ----
    {
        const int ct = wv;
        const int img = lane & 15, kq = lane >> 4;
        f16x8 wA3[4];
#pragma unroll
        for (int pos = 0; pos < 4; pos++)
            wA3[pos] = *(const f16x8*)&wb3g[(ct * 4 + pos) * 512 + lane * 8];
        const float4 b3v = *(const float4*)&b3[ct * 16 + kq * 4];
#pragma unroll 4
        for (int p = 0; p < 16; p++) {
            const int py = p >> 2, px = p & 3;
            f32x4 acc = {0.f, 0.f, 0.f, 0.f};
#pragma unroll
            for (int pos = 0; pos < 4; pos++) {
                const int pix = (py + (pos >> 1)) * 5 + px + (pos & 1);
                const f16x8 bv = *(const f16x8*)&c2s[img * 808 + pix * 32 + kq * 8];
                acc = __builtin_amdgcn_mfma_f32_16x16x32_f16(wA3[pos], bv, acc, 0, 0, 0);
            }
            unsigned short r4[4];
            r4[0] = f2h(fmaxf(acc[0] + b3v.x, 0.0f));
            r4[1] = f2h(fmaxf(acc[1] + b3v.y, 0.0f));
            r4[2] = f2h(fmaxf(acc[2] + b3v.z, 0.0f));
            r4[3] = f2h(fmaxf(acc[3] + b3v.w, 0.0f));
            *(ushort4v*)&c3s[img * 1032 + p * 64 + ct * 16 + kq * 4] = *(ushort4v*)&r4[0];
        }
    }
    __syncthreads();

    // ---- dump c3s -> featb (feat row already in permuted k'=p*64+co order) ----
#pragma unroll
    for (int i = 0; i < 8; i++) {
        const int gi = i * 2048 + tid * 8;
        const int img = gi >> 10, flat = gi & 1023;
        *(ushort8v*)&featb[(size_t)(base + img) * 1024 + flat] =
            *(const ushort8v*)&c3s[img * 1032 + flat];
    }
}

// ---------------------------------------------------------------------------
// K3: xproj[32768,512] = featb[32768,1024]_f16 @ wb[512,1024]_f16^T (fp32 out)
//   128x128 tile, BK=32, double-buffered stage-ahead, 1 barrier per K-step.
//   XCD-chunked blockIdx swizzle (1024 % 8 == 0 -> simple bijective form):
//   each XCD gets a contiguous by-range so the 4 blocks sharing an A-panel
//   run on the same XCD L2 instead of 4 different ones.
// ---------------------------------------------------------------------------
__global__ __launch_bounds__(256, 2) void gemm_xproj_mfma(
    const unsigned short* __restrict__ A,
    const unsigned short* __restrict__ W,
    float* __restrict__ C)
{
    __shared__ unsigned short As[2][128 * 32];
    __shared__ unsigned short Bs[2][128 * 32];

    const int tid  = threadIdx.x;
    // XCD-chunked swizzle: nwg=1024, NXCD=8, chunk=128
    const int wg = (blockIdx.x & 7) * 128 + (blockIdx.x >> 3);
    const int bx = wg & 3;
    const int by = wg >> 2;
    const int m0 = by * 128, n0 = bx * 128;
    const int lane = tid & 63, wave = tid >> 6;
    const int wm = (wave >> 1) * 64, wn = (wave & 1) * 64;
    const int srow = tid >> 2, sseg = tid & 3;

    const unsigned short* Ag = A + (size_t)(m0 + srow) * 1024 + sseg * 8;
    const unsigned short* Wg = W + (size_t)(n0 + srow) * 1024 + sseg * 8;

    f32x4 acc[4][4];
#pragma unroll
    for (int i = 0; i < 4; i++)
#pragma unroll
        for (int j = 0; j < 4; j++) acc[i][j] = (f32x4){0.f, 0.f, 0.f, 0.f};

    const int fr = lane & 15, fq = lane >> 4;

#define STAGEK(bb, k0) do {                                                \
        GLDS16(Ag + (k0),             (char*)&As[bb][0] + tid * 16);       \
        GLDS16(Ag + (k0) + 64 * 1024, (char*)&As[bb][0] + tid * 16 + 4096);\
        GLDS16(Wg + (k0),             (char*)&Bs[bb][0] + tid * 16);       \
        GLDS16(Wg + (k0) + 64 * 1024, (char*)&Bs[bb][0] + tid * 16 + 4096);\
    } while (0)

    STAGEK(0, 0);
    asm volatile("s_waitcnt vmcnt(0)" ::: "memory");
    __syncthreads();

    int cur = 0;
    for (int ks = 0; ks < 32; ks++) {
        if (ks + 1 < 32) STAGEK(cur ^ 1, (ks + 1) * 32);   // fly under MFMA

        f16x8 af[4], bfv[4];
#pragma unroll
        for (int i = 0; i < 4; i++)
            af[i] = *(const f16x8*)&As[cur][(wm + i * 16 + fr) * 32 + fq * 8];
#pragma unroll
        for (int j = 0; j < 4; j++)
            bfv[j] = *(const f16x8*)&Bs[cur][(wn + j * 16 + fr) * 32 + fq * 8];
#pragma unroll
        for (int i = 0; i < 4; i++)
#pragma unroll
            for (int j = 0; j < 4; j++)
                acc[i][j] = __builtin_amdgcn_mfma_f32_16x16x32_f16(af[i], bfv[j], acc[i][j], 0, 0, 0);

        asm volatile("s_waitcnt vmcnt(0)" ::: "memory");
        __syncthreads();
        cur ^= 1;
    }
#undef STAGEK

    const int cr = fq * 4, cc = fr;
#pragma unroll
    for (int i = 0; i < 4; i++) {
#pragma unroll
        for (int j = 0; j < 4; j++) {
            float* cp = &C[(size_t)(m0 + wm + i * 16 + cr) * 512 + (n0 + wn + j * 16 + cc)];
#pragma unroll
            for (int r = 0; r < 4; r++)
                cp[(size_t)r * 512] = acc[i][j][r];
        }
    }
}

// ---------------------------------------------------------------------------
// K4: 1-barrier butterfly LSTM (round-6 winner, verbatim).
//   256 blocks (1 batch elem each) x 512 threads (8 waves = 2/SIMD).
//   amdgpu_waves_per_eu(2,2) keeps the 64-VGPR w_hh block resident.
//   Thread (ci = tid>>2, s = tid&3): w_hh rows {g*128+ci} cols [32s,32s+32)
//   in VGPRs; 64 dot2 in 8 chains; DPP quad_perm butterfly; activations via
//   v_exp_f32+v_rcp_f32; hid stored fp16.
// ---------------------------------------------------------------------------
__global__ __launch_bounds__(512) __attribute__((amdgpu_waves_per_eu(2, 2)))
void lstm_bfly(
    const float* __restrict__ xproj, const float* __restrict__ done,
    const float* __restrict__ h0, const float* __restrict__ c0,
    const unsigned short* __restrict__ whhr,
    const float* __restrict__ b_ih, const float* __restrict__ b_hh,
    unsigned short* __restrict__ hid16, float* __restrict__ out)
{
    const int b   = blockIdx.x;
    const int tid = threadIdx.x;
    const int ci  = tid >> 2;        // cell 0..127
    const int s   = tid & 3;         // k-quarter 0..3

    __shared__ __align__(16) _Float16 hbuf[2][HID];

    // ---- resident weights: w[g][i] = w_hh[g*128+ci][s*32 + i*8 .. +8) ----
    f16x8 w[4][4];
    {
        const unsigned short* wp = whhr + (size_t)tid * 128;
#pragma unroll
        for (int g = 0; g < 4; g++)
#pragma unroll
            for (int i = 0; i < 4; i++)
                w[g][i] = *(const f16x8*)&wp[g * 32 + i * 8];
    }
    // ---- this lane's gate row (original order): n = s*128 + ci ----
    const float bias_l = b_ih[s * 128 + ci] + b_hh[s * 128 + ci];

    // ---- redundant cell state (identical across the 4 lanes of a cell) ----
    float c = c0[b * HID + ci];
    float h = h0[b * HID + ci];
    float dcur = done[b];

    if (tid < HID)
        hbuf[0][tid] = (_Float16)(h0[b * HID + tid] * (1.0f - dcur));

    // step-0 gate input (row ci*4+s thanks to the prep row-perm)
    float xq = bias_l + xproj[(size_t)b * 512 + ci * 4 + s];
    __syncthreads();

// one pair-block of the dot: 1 ds_read_b128 + 16 dot2 into chains c0..c3
#define DOTBLK(i, c0_, c1_, c2_, c3_)                                           \
    {                                                                           \
        const f16x8 hv8 = *(const f16x8*)&hbuf[p][s * 32 + (i) * 8];            \
        const f16x2 hp0 = P0(hv8), hp1 = P1(hv8), hp2 = P2(hv8), hp3 = P3(hv8); \
        c0_ = dot2_(P0(w[0][i]), hp0, c0_); c0_ = dot2_(P1(w[0][i]), hp1, c0_); \
        c0_ = dot2_(P2(w[0][i]), hp2, c0_); c0_ = dot2_(P3(w[0][i]), hp3, c0_); \
        c1_ = dot2_(P0(w[1][i]), hp0, c1_); c1_ = dot2_(P1(w[1][i]), hp1, c1_); \
        c1_ = dot2_(P2(w[1][i]), hp2, c1_); c1_ = dot2_(P3(w[1][i]), hp3, c1_); \
        c2_ = dot2_(P0(w[2][i]), hp0, c2_); c2_ = dot2_(P1(w[2][i]), hp1, c2_); \
        c2_ = dot2_(P2(w[2][i]), hp2, c2_); c2_ = dot2_(P3(w[2][i]), hp3, c2_); \
        c3_ = dot2_(P0(w[3][i]), hp0, c3_); c3_ = dot2_(P1(w[3][i]), hp1, c3_); \
        c3_ = dot2_(P2(w[3][i]), hp2, c3_); c3_ = dot2_(P3(w[3][i]), hp3, c3_); \
    }

    int p = 0;
    for (int t = 0; t < T_LEN; t++) {
        // ---- prefetch next-step xproj/done (hides under the dot loop) ----
        const int tn = (t + 1 < T_LEN) ? t + 1 : t;
        const float xqn = bias_l + xproj[((size_t)tn * B_ENV + b) * 512 + ci * 4 + s];
        const float dnn = done[tn * B_ENV + b];

        // ---- 64 dot2 in 8 independent chains ----
        float a0 = (s == 0) ? xq : 0.0f;
        float a1 = (s == 1) ? xq : 0.0f;
        float a2 = (s == 2) ? xq : 0.0f;
        float a3 = (s == 3) ? xq : 0.0f;
        float b0 = 0.f, b1 = 0.f, b2 = 0.f, b3 = 0.f;
        DOTBLK(0, a0, a1, a2, a3)
        DOTBLK(1, b0, b1, b2, b3)
        DOTBLK(2, a0, a1, a2, a3)
        DOTBLK(3, b0, b1, b2, b3)
        a0 += b0; a1 += b1; a2 += b2; a3 += b3;

        // ---- DPP quad butterfly (pure VALU, no LDS) ----
        a0 = bfly_sum4(a0); a1 = bfly_sum4(a1);
        a2 = bfly_sum4(a2); a3 = bfly_sum4(a3);

        // ---- fast activations + update (identical in all 4 lanes) ----
        const float gi = sigm_(a0), gf = sigm_(a1);
        const float gg = tanh_(a2), go = sigm_(a3);
        const float m = 1.0f - dcur;
        c = fmaf(gf, c * m, gi * gg);
        h = go * tanh_(c);

        if (s == 0) {
            hid16[((size_t)t * B_ENV + b) * HID + ci] = f2h(h);
            hbuf[p ^ 1][ci] = (_Float16)(h * (1.0f - dnn));
        }

        xq = xqn; dcur = dnn; p ^= 1;
        __syncthreads();
    }

    if (s == 0) {
        out[262144 + b * HID + ci] = h;
        out[294912 + b * HID + ci] = c;
    }
#undef DOTBLK
}

// ---------------------------------------------------------------------------
// K5: heads. out[n][0..6] = actor, out[n][7] = critic. 32 rows / block.
// ---------------------------------------------------------------------------
__global__ __launch_bounds__(256, 2) void heads_kernel(
    const unsigned short* __restrict__ hid16,
    const float* __restrict__ aw, const float* __restrict__ ab,
    const float* __restrict__ cw, const float* __restrict__ cb,
    float* __restrict__ out)
{
    __shared__ float hs[32 * 129];
    __shared__ float ws[8 * 130];
    __shared__ float bs[8];

    const int tid = threadIdx.x;
    const int n0 = blockIdx.x * 32;

    for (int i = tid; i < 1024; i += 256) {
        const int r = i >> 7, k = i & 127;
        ws[r * 130 + k] = (r < 7) ? aw[r * 128 + k] : cw[k];
    }
    if (tid < 8) bs[tid] = (tid < 7) ? ab[tid] : cb[0];
    // staged fp16 -> fp32 conversion, 8 halves per thread iteration
    for (int i = tid; i < 512; i += 256) {
        const int r = i >> 4, k8 = (i & 15) * 8;
        const ushort8v v = *(const ushort8v*)&hid16[(size_t)(n0 + r) * 128 + k8];
#pragma unroll
        for (int q = 0; q < 8; q++) {
            union { unsigned short u; _Float16 h; } un; un.u = v[q];
            hs[r * 129 + k8 + q] = (float)un.h;
        }
    }
    __syncthreads();

    const int r = tid >> 3, jj = tid & 7;
    float acc = bs[jj];
    const float* hp = &hs[r * 129];
    const float* wp = &ws[jj * 130];
#pragma unroll
    for (int k = 0; k < 128; k++) acc = fmaf(hp[k], wp[k], acc);
    out[(size_t)(n0 + r) * 8 + jj] = acc;
}

// ---------------------------------------------------------------------------
extern "C" void kernel_launch(void* const* d_in, const int* in_sizes, int n_in,
                              void* d_out, int out_size, void* d_ws, size_t ws_size,
                              hipStream_t stream)
{
    (void)in_sizes; (void)n_in; (void)out_size; (void)ws_size;

    const float* obs  = (const float*)d_in[0];
    const float* done = (const float*)d_in[1];
    const float* h0   = (const float*)d_in[2];
    const float* c0   = (const float*)d_in[3];
    const float* w1   = (const float*)d_in[4];
    const float* b1   = (const float*)d_in[5];
    const float* w2   = (const float*)d_in[6];
    const float* b2   = (const float*)d_in[7];
    const float* w3   = (const float*)d_in[8];
    const float* b3   = (const float*)d_in[9];
    const float* w_ih = (const float*)d_in[10];
    const float* w_hh = (const float*)d_in[11];
    const float* b_ih = (const float*)d_in[12];
    const float* b_hh = (const float*)d_in[13];
    const float* aw   = (const float*)d_in[14];
    const float* ab   = (const float*)d_in[15];
    const float* cw   = (const float*)d_in[16];
    const float* cb   = (const float*)d_in[17];
    float* out = (float*)d_out;

    unsigned short* featb = (unsigned short*)d_ws;     // 33,554,432 u16
    unsigned short* wb    = featb + 33554432ull;       //    524,288 u16
    unsigned short* wb2g  = wb    + 524288ull;         //      2,048 u16
    unsigned short* wb3g  = wb2g  + 2048ull;           //      8,192 u16
    float* xproj = (float*)(wb3g + 8192ull + 2048ull); // align pad; 16,777,216 f32
    unsigned short* hid16 = (unsigned short*)(xproj + 16777216ull); // 4,194,304 u16
    unsigned short* whhr  = hid16 + 4194304ull;        // 65,536 u16

    prep_all<<<2344, 256, 0, stream>>>(w_ih, wb, w2, w3, wb2g, wb3g, w_hh, whhr);
    conv_fused<<<2048, 256, 0, stream>>>(obs, w1, b1, b2, b3, wb2g, wb3g, featb);
    gemm_xproj_mfma<<<1024, 256, 0, stream>>>(featb, wb, xproj);
    lstm_bfly<<<256, 512, 0, stream>>>(xproj, done, h0, c0, whhr, b_ih, b_hh, hid16, out);
    heads_kernel<<<1024, 256, 0, stream>>>(hid16, aw, ab, cw, cb, out);
}